// Round 1
// baseline (384.897 us; speedup 1.0000x reference)
//
#include <hip/hip_runtime.h>
#include <stdint.h>

// ---------------------------------------------------------------------------
// StructureAE: h = x@W ; GAT edge softmax aggregate ; embed = leaky(out) ;
// recon = sigmoid(embed @ embed^T)
// N=10000, in_dim=512, out_dim=128, E=320000 (+N self loops)
// d_out = [recon (N*N f32), embed (N*128 f32)]
// ---------------------------------------------------------------------------

typedef __attribute__((ext_vector_type(8))) short short8v;  // 8 bf16 (4 VGPR)
typedef __attribute__((ext_vector_type(4))) float f32x4;

#define IN_DIM 512
#define OUT_DIM 128
#define NEG_ATT 0.5f
#define NEG_ACT 0.01f

__device__ __forceinline__ float leakyf(float v, float s) { return v >= 0.f ? v : s * v; }

__device__ __forceinline__ uint16_t f2bf(float v) {
  uint32_t u = __float_as_uint(v);
  u += 0x7FFFu + ((u >> 16) & 1u);   // round-to-nearest-even
  return (uint16_t)(u >> 16);
}
__device__ __forceinline__ float bf2f(uint16_t b) { return __uint_as_float(((uint32_t)b) << 16); }

// ---------------- h = x @ W  (f32, 64-row tile, K-tiles of 64) --------------
__global__ __launch_bounds__(256) void k_h_gemm(const float* __restrict__ x,
                                                const float* __restrict__ W,
                                                float* __restrict__ h, int N) {
  __shared__ float sX[64][64];    // 16 KB
  __shared__ float sW[64][128];   // 32 KB
  int tid = threadIdx.x;
  int rowBase = blockIdx.x * 64;
  int tx = tid & 31, ty = tid >> 5;   // 32 col-groups x 8 row-groups
  float acc[8][4] = {};
  for (int kt = 0; kt < IN_DIM / 64; ++kt) {
    #pragma unroll
    for (int i = 0; i < 4; ++i) {            // 64x64 = 1024 float4
      int idx = tid + i * 256;
      int r = idx >> 4, c4 = idx & 15;
      int gr = rowBase + r;
      float4 v = make_float4(0.f, 0.f, 0.f, 0.f);
      if (gr < N) v = *(const float4*)&x[(size_t)gr * IN_DIM + kt * 64 + c4 * 4];
      *(float4*)&sX[r][c4 * 4] = v;
    }
    #pragma unroll
    for (int i = 0; i < 8; ++i) {            // 64x128 = 2048 float4
      int idx = tid + i * 256;
      int r = idx >> 5, c4 = idx & 31;
      *(float4*)&sW[r][c4 * 4] = *(const float4*)&W[(size_t)(kt * 64 + r) * OUT_DIM + c4 * 4];
    }
    __syncthreads();
    for (int k = 0; k < 64; k += 4) {
      float4 wreg[4];
      #pragma unroll
      for (int kk = 0; kk < 4; ++kk) wreg[kk] = *(const float4*)&sW[k + kk][tx * 4];
      #pragma unroll
      for (int i = 0; i < 8; ++i) {
        float4 xr = *(const float4*)&sX[ty * 8 + i][k];
        const float* xv = (const float*)&xr;
        #pragma unroll
        for (int kk = 0; kk < 4; ++kk) {
          acc[i][0] = fmaf(xv[kk], wreg[kk].x, acc[i][0]);
          acc[i][1] = fmaf(xv[kk], wreg[kk].y, acc[i][1]);
          acc[i][2] = fmaf(xv[kk], wreg[kk].z, acc[i][2]);
          acc[i][3] = fmaf(xv[kk], wreg[kk].w, acc[i][3]);
        }
      }
    }
    __syncthreads();
  }
  #pragma unroll
  for (int i = 0; i < 8; ++i) {
    int row = rowBase + ty * 8 + i;
    if (row < N) {
      float4 v = make_float4(acc[i][0], acc[i][1], acc[i][2], acc[i][3]);
      *(float4*)&h[(size_t)row * OUT_DIM + tx * 4] = v;
    }
  }
}

// ---------------- a_src/a_dst: per-row dot with att vectors -----------------
__global__ __launch_bounds__(256) void k_att(const float* __restrict__ h,
                                             const float* __restrict__ att_s,
                                             const float* __restrict__ att_d,
                                             float* __restrict__ a_src,
                                             float* __restrict__ a_dst, int N) {
  int wid = (int)((blockIdx.x * blockDim.x + threadIdx.x) >> 6);
  int lane = threadIdx.x & 63;
  if (wid >= N) return;
  float v0 = h[(size_t)wid * OUT_DIM + lane];
  float v1 = h[(size_t)wid * OUT_DIM + 64 + lane];
  float ps = v0 * att_s[lane] + v1 * att_s[64 + lane];
  float pd = v0 * att_d[lane] + v1 * att_d[64 + lane];
  #pragma unroll
  for (int off = 32; off; off >>= 1) {
    ps += __shfl_xor(ps, off);
    pd += __shfl_xor(pd, off);
  }
  if (lane == 0) { a_src[wid] = ps; a_dst[wid] = pd; }
}

// ---------------- CSR build --------------------------------------------------
__global__ void k_zero(int* __restrict__ p, int n) {
  int i = blockIdx.x * blockDim.x + threadIdx.x;
  if (i < n) p[i] = 0;
}
__global__ void k_count(const int* __restrict__ dst, int* __restrict__ cnt, int E) {
  int e = blockIdx.x * blockDim.x + threadIdx.x;
  if (e < E) atomicAdd(&cnt[dst[e]], 1);
}
__global__ __launch_bounds__(1024) void k_scan(const int* __restrict__ cnt,
                                               int* __restrict__ row_start, int N) {
  __shared__ int sd[1024];
  int t = threadIdx.x;
  const int CH = (N + 1023) >> 10;
  int base = t * CH;
  int s = 0;
  for (int k = 0; k < CH; ++k) { int i = base + k; if (i < N) s += cnt[i]; }
  sd[t] = s;
  __syncthreads();
  for (int off = 1; off < 1024; off <<= 1) {
    int v = (t >= off) ? sd[t - off] : 0;
    __syncthreads();
    sd[t] += v;
    __syncthreads();
  }
  int run = (t == 0) ? 0 : sd[t - 1];
  for (int k = 0; k < CH; ++k) {
    int i = base + k;
    if (i < N) { row_start[i] = run; run += cnt[i]; }
  }
  if (t == 1023) row_start[N] = sd[1023];
}
__global__ void k_copy(const int* __restrict__ a, int* __restrict__ b, int n) {
  int i = blockIdx.x * blockDim.x + threadIdx.x;
  if (i < n) b[i] = a[i];
}
__global__ void k_fill(const int* __restrict__ src, const int* __restrict__ dst,
                       int* __restrict__ cursor, int* __restrict__ csr, int E) {
  int e = blockIdx.x * blockDim.x + threadIdx.x;
  if (e < E) {
    int d = dst[e];
    int pos = atomicAdd(&cursor[d], 1);
    csr[pos] = src[e];
  }
}

// ---------------- zero bf16 pad rows ----------------------------------------
__global__ void k_pad(uint16_t* __restrict__ ehi, uint16_t* __restrict__ elo,
                      int N, int NPAD) {
  int total = (NPAD - N) * OUT_DIM;
  for (int i = threadIdx.x + blockIdx.x * blockDim.x; i < total; i += blockDim.x * gridDim.x) {
    ehi[(size_t)N * OUT_DIM + i] = 0;
    elo[(size_t)N * OUT_DIM + i] = 0;
  }
}

// ---------------- per-dst softmax aggregation (one wave per node) -----------
__global__ __launch_bounds__(256) void k_aggregate(
    const float* __restrict__ h, const float* __restrict__ a_src,
    const float* __restrict__ a_dst, const int* __restrict__ row_start,
    const int* __restrict__ csr, const float* __restrict__ bias,
    float* __restrict__ embed_out, uint16_t* __restrict__ ehi,
    uint16_t* __restrict__ elo, int N) {
  int wid = (int)((blockIdx.x * blockDim.x + threadIdx.x) >> 6);
  int lane = threadIdx.x & 63;
  if (wid >= N) return;
  int i = wid;
  int s0 = row_start[i], s1 = row_start[i + 1];
  float adst = a_dst[i];
  float eself = leakyf(a_src[i] + adst, NEG_ATT);
  // pass 1: max
  float m = eself;
  for (int k = s0 + lane; k < s1; k += 64) {
    float e = leakyf(a_src[csr[k]] + adst, NEG_ATT);
    m = fmaxf(m, e);
  }
  #pragma unroll
  for (int off = 32; off; off >>= 1) m = fmaxf(m, __shfl_xor(m, off));
  // pass 2: denom
  float dsum = 0.f;
  for (int k = s0 + lane; k < s1; k += 64) {
    float e = leakyf(a_src[csr[k]] + adst, NEG_ATT);
    dsum += __expf(e - m);
  }
  #pragma unroll
  for (int off = 32; off; off >>= 1) dsum += __shfl_xor(dsum, off);
  dsum += __expf(eself - m);
  float inv = 1.0f / dsum;
  // pass 3: weighted sum (all 64 lanes cooperate per edge; 2 dims/lane)
  float wself = __expf(eself - m) * inv;
  float acc0 = h[(size_t)i * OUT_DIM + lane] * wself;
  float acc1 = h[(size_t)i * OUT_DIM + 64 + lane] * wself;
  #pragma unroll 4
  for (int k = s0; k < s1; ++k) {
    int s = csr[k];  // uniform across wave
    float w = __expf(leakyf(a_src[s] + adst, NEG_ATT) - m) * inv;
    acc0 = fmaf(h[(size_t)s * OUT_DIM + lane], w, acc0);
    acc1 = fmaf(h[(size_t)s * OUT_DIM + 64 + lane], w, acc1);
  }
  float o0 = leakyf(acc0 + bias[lane], NEG_ACT);
  float o1 = leakyf(acc1 + bias[64 + lane], NEG_ACT);
  embed_out[(size_t)i * OUT_DIM + lane] = o0;
  embed_out[(size_t)i * OUT_DIM + 64 + lane] = o1;
  // bf16 hi/lo split for the recon MFMA
  uint16_t h0 = f2bf(o0), h1 = f2bf(o1);
  uint16_t l0 = f2bf(o0 - bf2f(h0)), l1 = f2bf(o1 - bf2f(h1));
  ehi[(size_t)i * OUT_DIM + lane] = h0;
  ehi[(size_t)i * OUT_DIM + 64 + lane] = h1;
  elo[(size_t)i * OUT_DIM + lane] = l0;
  elo[(size_t)i * OUT_DIM + 64 + lane] = l1;
}

// ---------------- recon = sigmoid(embed @ embed^T) via bf16-split MFMA ------
// Block: 256 thr = 4 waves, 128x128 output tile; wave -> 64x64 (4x4 subtiles
// of 16x16). Fragments gathered straight from L2 (emb hi/lo = 5 MB).
// mfma_f32_16x16x32_bf16: A/B lane holds row/col = lane&15, k = 8*(lane>>4)+j;
// C/D: col = lane&15, row = (lane>>4)*4 + reg.
__global__ __launch_bounds__(256) void k_recon(const uint16_t* __restrict__ ehi,
                                               const uint16_t* __restrict__ elo,
                                               float* __restrict__ out, int N) {
  int tid = threadIdx.x;
  int wave = tid >> 6, lane = tid & 63;
  int rowBlk = blockIdx.y * 128 + (wave >> 1) * 64;
  int colBlk = blockIdx.x * 128 + (wave & 1) * 64;
  int r16 = lane & 15;
  int kg = lane >> 4;

  f32x4 acc[4][4];
  #pragma unroll
  for (int a = 0; a < 4; ++a)
    #pragma unroll
    for (int b = 0; b < 4; ++b) acc[a][b] = (f32x4){0.f, 0.f, 0.f, 0.f};

  #pragma unroll
  for (int kc = 0; kc < 4; ++kc) {   // 4 chunks of K=32
    int kOff = kc * 32 + kg * 8;
    short8v ahi[4], alo[4], bhi[4], blo[4];
    #pragma unroll
    for (int t = 0; t < 4; ++t) {
      size_t ar = (size_t)(rowBlk + t * 16 + r16) * OUT_DIM + kOff;
      size_t bc = (size_t)(colBlk + t * 16 + r16) * OUT_DIM + kOff;
      ahi[t] = *(const short8v*)&ehi[ar];
      alo[t] = *(const short8v*)&elo[ar];
      bhi[t] = *(const short8v*)&ehi[bc];
      blo[t] = *(const short8v*)&elo[bc];
    }
    #pragma unroll
    for (int ti = 0; ti < 4; ++ti)
      #pragma unroll
      for (int tj = 0; tj < 4; ++tj) {
        acc[ti][tj] = __builtin_amdgcn_mfma_f32_16x16x32_bf16(ahi[ti], bhi[tj], acc[ti][tj], 0, 0, 0);
        acc[ti][tj] = __builtin_amdgcn_mfma_f32_16x16x32_bf16(ahi[ti], blo[tj], acc[ti][tj], 0, 0, 0);
        acc[ti][tj] = __builtin_amdgcn_mfma_f32_16x16x32_bf16(alo[ti], bhi[tj], acc[ti][tj], 0, 0, 0);
      }
  }
  #pragma unroll
  for (int ti = 0; ti < 4; ++ti) {
    int rb = rowBlk + ti * 16 + kg * 4;
    #pragma unroll
    for (int tj = 0; tj < 4; ++tj) {
      int c = colBlk + tj * 16 + r16;
      if (c < N) {
        #pragma unroll
        for (int q = 0; q < 4; ++q) {
          int r = rb + q;
          if (r < N) {
            float z = acc[ti][tj][q];
            out[(size_t)r * N + c] = 1.0f / (1.0f + __expf(-z));
          }
        }
      }
    }
  }
}

// ---------------------------------------------------------------------------
extern "C" void kernel_launch(void* const* d_in, const int* in_sizes, int n_in,
                              void* d_out, int out_size, void* d_ws, size_t ws_size,
                              hipStream_t stream) {
  const float* x = (const float*)d_in[0];
  const int* ei = (const int*)d_in[1];
  const float* W = (const float*)d_in[2];
  const float* att_s = (const float*)d_in[3];
  const float* att_d = (const float*)d_in[4];
  const float* bias = (const float*)d_in[5];

  const int N = in_sizes[0] / IN_DIM;   // 10000
  const int E = in_sizes[1] / 2;        // 320000
  const int NPAD = ((N + 127) / 128) * 128;  // 10112

  float* out = (float*)d_out;
  float* embed_out = out + (size_t)N * N;

  // workspace layout (16B-aligned at ehi)
  float* h = (float*)d_ws;                      // N*128 f32
  float* a_src = h + (size_t)N * OUT_DIM;       // N
  float* a_dst = a_src + N;                     // N
  int* cnt = (int*)(a_dst + N);                 // N
  int* row_start = cnt + N;                     // N+4 (padded)
  int* cursor = row_start + (N + 4);            // N
  int* csr = cursor + N;                        // E
  uint16_t* ehi = (uint16_t*)(csr + E);         // NPAD*128 bf16
  uint16_t* elo = ehi + (size_t)NPAD * OUT_DIM; // NPAD*128 bf16

  const int* e_src = ei;
  const int* e_dst = ei + E;

  k_h_gemm<<<dim3((N + 63) / 64), 256, 0, stream>>>(x, W, h, N);
  k_att<<<dim3((N * 64 + 255) / 256), 256, 0, stream>>>(h, att_s, att_d, a_src, a_dst, N);
  k_zero<<<dim3((N + 255) / 256), 256, 0, stream>>>(cnt, N);
  k_count<<<dim3((E + 255) / 256), 256, 0, stream>>>(e_dst, cnt, E);
  k_scan<<<dim3(1), 1024, 0, stream>>>(cnt, row_start, N);
  k_copy<<<dim3((N + 255) / 256), 256, 0, stream>>>(row_start, cursor, N);
  k_fill<<<dim3((E + 255) / 256), 256, 0, stream>>>(e_src, e_dst, cursor, csr, E);
  k_pad<<<dim3(8), 256, 0, stream>>>(ehi, elo, N, NPAD);
  k_aggregate<<<dim3((N * 64 + 255) / 256), 256, 0, stream>>>(
      h, a_src, a_dst, row_start, csr, bias, embed_out, ehi, elo, N);
  k_recon<<<dim3(NPAD / 128, NPAD / 128), 256, 0, stream>>>(ehi, elo, out, N);
}

// Round 2
// 377.218 us; speedup vs baseline: 1.0204x; 1.0204x over previous
//
#include <hip/hip_runtime.h>
#include <stdint.h>

// ---------------------------------------------------------------------------
// StructureAE: h = x@W ; GAT edge softmax aggregate ; embed = leaky(out) ;
// recon = sigmoid(embed @ embed^T)
// N=10000, in_dim=512, out_dim=128, E=320000 (+N self loops)
// d_out = [recon (N*N f32), embed (N*128 f32)]
// ---------------------------------------------------------------------------

typedef __attribute__((ext_vector_type(8))) short short8v;  // 8 bf16 (4 VGPR)
typedef __attribute__((ext_vector_type(4))) float f32x4;

#define IN_DIM 512
#define OUT_DIM 128
#define NEG_ATT 0.5f
#define NEG_ACT 0.01f

__device__ __forceinline__ float leakyf(float v, float s) { return v >= 0.f ? v : s * v; }

__device__ __forceinline__ uint16_t f2bf(float v) {
  uint32_t u = __float_as_uint(v);
  u += 0x7FFFu + ((u >> 16) & 1u);   // round-to-nearest-even
  return (uint16_t)(u >> 16);
}
__device__ __forceinline__ float bf2f(uint16_t b) { return __uint_as_float(((uint32_t)b) << 16); }

// ---------------- h = x @ W  (f32, 64-row tile, K-tiles of 64) --------------
__global__ __launch_bounds__(256) void k_h_gemm(const float* __restrict__ x,
                                                const float* __restrict__ W,
                                                float* __restrict__ h, int N) {
  __shared__ float sX[64][64];    // 16 KB
  __shared__ float sW[64][128];   // 32 KB
  int tid = threadIdx.x;
  int rowBase = blockIdx.x * 64;
  int tx = tid & 31, ty = tid >> 5;   // 32 col-groups x 8 row-groups
  float acc[8][4] = {};
  for (int kt = 0; kt < IN_DIM / 64; ++kt) {
    #pragma unroll
    for (int i = 0; i < 4; ++i) {            // 64x64 = 1024 float4
      int idx = tid + i * 256;
      int r = idx >> 4, c4 = idx & 15;
      int gr = rowBase + r;
      float4 v = make_float4(0.f, 0.f, 0.f, 0.f);
      if (gr < N) v = *(const float4*)&x[(size_t)gr * IN_DIM + kt * 64 + c4 * 4];
      *(float4*)&sX[r][c4 * 4] = v;
    }
    #pragma unroll
    for (int i = 0; i < 8; ++i) {            // 64x128 = 2048 float4
      int idx = tid + i * 256;
      int r = idx >> 5, c4 = idx & 31;
      *(float4*)&sW[r][c4 * 4] = *(const float4*)&W[(size_t)(kt * 64 + r) * OUT_DIM + c4 * 4];
    }
    __syncthreads();
    for (int k = 0; k < 64; k += 4) {
      float4 wreg[4];
      #pragma unroll
      for (int kk = 0; kk < 4; ++kk) wreg[kk] = *(const float4*)&sW[k + kk][tx * 4];
      #pragma unroll
      for (int i = 0; i < 8; ++i) {
        float4 xr = *(const float4*)&sX[ty * 8 + i][k];
        const float* xv = (const float*)&xr;
        #pragma unroll
        for (int kk = 0; kk < 4; ++kk) {
          acc[i][0] = fmaf(xv[kk], wreg[kk].x, acc[i][0]);
          acc[i][1] = fmaf(xv[kk], wreg[kk].y, acc[i][1]);
          acc[i][2] = fmaf(xv[kk], wreg[kk].z, acc[i][2]);
          acc[i][3] = fmaf(xv[kk], wreg[kk].w, acc[i][3]);
        }
      }
    }
    __syncthreads();
  }
  #pragma unroll
  for (int i = 0; i < 8; ++i) {
    int row = rowBase + ty * 8 + i;
    if (row < N) {
      float4 v = make_float4(acc[i][0], acc[i][1], acc[i][2], acc[i][3]);
      *(float4*)&h[(size_t)row * OUT_DIM + tx * 4] = v;
    }
  }
}

// ---------------- a_src/a_dst: per-row dot with att vectors -----------------
__global__ __launch_bounds__(256) void k_att(const float* __restrict__ h,
                                             const float* __restrict__ att_s,
                                             const float* __restrict__ att_d,
                                             float* __restrict__ a_src,
                                             float* __restrict__ a_dst, int N) {
  int wid = (int)((blockIdx.x * blockDim.x + threadIdx.x) >> 6);
  int lane = threadIdx.x & 63;
  if (wid >= N) return;
  float v0 = h[(size_t)wid * OUT_DIM + lane];
  float v1 = h[(size_t)wid * OUT_DIM + 64 + lane];
  float ps = v0 * att_s[lane] + v1 * att_s[64 + lane];
  float pd = v0 * att_d[lane] + v1 * att_d[64 + lane];
  #pragma unroll
  for (int off = 32; off; off >>= 1) {
    ps += __shfl_xor(ps, off);
    pd += __shfl_xor(pd, off);
  }
  if (lane == 0) { a_src[wid] = ps; a_dst[wid] = pd; }
}

// ---------------- CSR build --------------------------------------------------
__global__ void k_zero(int* __restrict__ p, int n) {
  int i = blockIdx.x * blockDim.x + threadIdx.x;
  if (i < n) p[i] = 0;
}
__global__ void k_count(const int* __restrict__ dst, int* __restrict__ cnt, int E) {
  int e = blockIdx.x * blockDim.x + threadIdx.x;
  if (e < E) atomicAdd(&cnt[dst[e]], 1);
}
__global__ __launch_bounds__(1024) void k_scan(const int* __restrict__ cnt,
                                               int* __restrict__ row_start, int N) {
  __shared__ int sd[1024];
  int t = threadIdx.x;
  const int CH = (N + 1023) >> 10;
  int base = t * CH;
  int s = 0;
  for (int k = 0; k < CH; ++k) { int i = base + k; if (i < N) s += cnt[i]; }
  sd[t] = s;
  __syncthreads();
  for (int off = 1; off < 1024; off <<= 1) {
    int v = (t >= off) ? sd[t - off] : 0;
    __syncthreads();
    sd[t] += v;
    __syncthreads();
  }
  int run = (t == 0) ? 0 : sd[t - 1];
  for (int k = 0; k < CH; ++k) {
    int i = base + k;
    if (i < N) { row_start[i] = run; run += cnt[i]; }
  }
  if (t == 1023) row_start[N] = sd[1023];
}
__global__ void k_copy(const int* __restrict__ a, int* __restrict__ b, int n) {
  int i = blockIdx.x * blockDim.x + threadIdx.x;
  if (i < n) b[i] = a[i];
}
__global__ void k_fill(const int* __restrict__ src, const int* __restrict__ dst,
                       int* __restrict__ cursor, int* __restrict__ csr, int E) {
  int e = blockIdx.x * blockDim.x + threadIdx.x;
  if (e < E) {
    int d = dst[e];
    int pos = atomicAdd(&cursor[d], 1);
    csr[pos] = src[e];
  }
}

// ---------------- zero bf16 pad rows ----------------------------------------
__global__ void k_pad(uint16_t* __restrict__ ehi, uint16_t* __restrict__ elo,
                      int N, int NPAD) {
  int total = (NPAD - N) * OUT_DIM;
  for (int i = threadIdx.x + blockIdx.x * blockDim.x; i < total; i += blockDim.x * gridDim.x) {
    ehi[(size_t)N * OUT_DIM + i] = 0;
    elo[(size_t)N * OUT_DIM + i] = 0;
  }
}

// ---------------- per-dst softmax aggregation (one wave per node) -----------
__global__ __launch_bounds__(256) void k_aggregate(
    const float* __restrict__ h, const float* __restrict__ a_src,
    const float* __restrict__ a_dst, const int* __restrict__ row_start,
    const int* __restrict__ csr, const float* __restrict__ bias,
    float* __restrict__ embed_out, uint16_t* __restrict__ ehi,
    uint16_t* __restrict__ elo, int N) {
  int wid = (int)((blockIdx.x * blockDim.x + threadIdx.x) >> 6);
  int lane = threadIdx.x & 63;
  if (wid >= N) return;
  int i = wid;
  int s0 = row_start[i], s1 = row_start[i + 1];
  float adst = a_dst[i];
  float eself = leakyf(a_src[i] + adst, NEG_ATT);
  // pass 1: max
  float m = eself;
  for (int k = s0 + lane; k < s1; k += 64) {
    float e = leakyf(a_src[csr[k]] + adst, NEG_ATT);
    m = fmaxf(m, e);
  }
  #pragma unroll
  for (int off = 32; off; off >>= 1) m = fmaxf(m, __shfl_xor(m, off));
  // pass 2: denom
  float dsum = 0.f;
  for (int k = s0 + lane; k < s1; k += 64) {
    float e = leakyf(a_src[csr[k]] + adst, NEG_ATT);
    dsum += __expf(e - m);
  }
  #pragma unroll
  for (int off = 32; off; off >>= 1) dsum += __shfl_xor(dsum, off);
  dsum += __expf(eself - m);
  float inv = 1.0f / dsum;
  // pass 3: weighted sum (all 64 lanes cooperate per edge; 2 dims/lane)
  float wself = __expf(eself - m) * inv;
  float acc0 = h[(size_t)i * OUT_DIM + lane] * wself;
  float acc1 = h[(size_t)i * OUT_DIM + 64 + lane] * wself;
  #pragma unroll 4
  for (int k = s0; k < s1; ++k) {
    int s = csr[k];  // uniform across wave
    float w = __expf(leakyf(a_src[s] + adst, NEG_ATT) - m) * inv;
    acc0 = fmaf(h[(size_t)s * OUT_DIM + lane], w, acc0);
    acc1 = fmaf(h[(size_t)s * OUT_DIM + 64 + lane], w, acc1);
  }
  float o0 = leakyf(acc0 + bias[lane], NEG_ACT);
  float o1 = leakyf(acc1 + bias[64 + lane], NEG_ACT);
  embed_out[(size_t)i * OUT_DIM + lane] = o0;
  embed_out[(size_t)i * OUT_DIM + 64 + lane] = o1;
  // bf16 hi/lo split for the recon MFMA
  uint16_t h0 = f2bf(o0), h1 = f2bf(o1);
  uint16_t l0 = f2bf(o0 - bf2f(h0)), l1 = f2bf(o1 - bf2f(h1));
  ehi[(size_t)i * OUT_DIM + lane] = h0;
  ehi[(size_t)i * OUT_DIM + 64 + lane] = h1;
  elo[(size_t)i * OUT_DIM + lane] = l0;
  elo[(size_t)i * OUT_DIM + 64 + lane] = l1;
}

// ---------------- recon = sigmoid(embed @ embed^T) via bf16-split MFMA ------
// Block: 512 thr = 8 waves (2 row-waves x 4 col-waves), 256x256 output tile.
// Wave -> 128x64 (8x4 subtiles of 16x16). Fragments gathered from L2.
// Epilogue: LDS-staged 64-row slices -> f32x4 nontemporal stores; each wave
// stores 1024B contiguous per instruction (full 128B lines -> no
// write-allocate HBM fetch).
// mfma_f32_16x16x32_bf16 A/B: lane holds row/col = lane&15, k = 8*(lane>>4)+j;
// C/D: col = lane&15, row = (lane>>4)*4 + reg.
__global__ __launch_bounds__(512, 2) void k_recon(const uint16_t* __restrict__ ehi,
                                                  const uint16_t* __restrict__ elo,
                                                  float* __restrict__ out,
                                                  int N, int nb) {
  __shared__ float sOut[64][260];   // 64x256 slice, +4 pad (16B-aligned rows)
  int tid = threadIdx.x;
  int wid = tid >> 6, lane = tid & 63;
  int wr = wid >> 2, wc = wid & 3;
  int r16 = lane & 15, kg = lane >> 4;

  // XCD-aware bijective swizzle (nwg = nb*nb, multiple of 8): each XCD gets
  // nwg/8 consecutive blocks in row-panel-major order -> A-panel L2-resident.
  int nwg = nb * nb;
  int orig = blockIdx.x;
  int swz = ((nwg & 7) == 0) ? ((orig & 7) * (nwg >> 3) + (orig >> 3)) : orig;
  int by = swz / nb, bx = swz - by * nb;
  int rowBlk = by * 256, colBlk = bx * 256;

  int rowA = rowBlk + wr * 128;   // + ti*16 + r16
  int rowB = colBlk + wc * 64;    // + tj*16 + r16

  f32x4 acc[8][4];
  #pragma unroll
  for (int a = 0; a < 8; ++a)
    #pragma unroll
    for (int b = 0; b < 4; ++b) acc[a][b] = (f32x4){0.f, 0.f, 0.f, 0.f};

  #pragma unroll
  for (int kc = 0; kc < 4; ++kc) {   // 4 chunks of K=32
    int kOff = kc * 32 + kg * 8;
    short8v bh[4], bl[4];
    #pragma unroll
    for (int tj = 0; tj < 4; ++tj) {
      size_t o = (size_t)(rowB + tj * 16 + r16) * OUT_DIM + kOff;
      bh[tj] = *(const short8v*)&ehi[o];
      bl[tj] = *(const short8v*)&elo[o];
    }
    #pragma unroll
    for (int ti = 0; ti < 8; ++ti) {
      size_t o = (size_t)(rowA + ti * 16 + r16) * OUT_DIM + kOff;
      short8v ah = *(const short8v*)&ehi[o];
      short8v al = *(const short8v*)&elo[o];
      #pragma unroll
      for (int tj = 0; tj < 4; ++tj) {
        acc[ti][tj] = __builtin_amdgcn_mfma_f32_16x16x32_bf16(ah, bh[tj], acc[ti][tj], 0, 0, 0);
        acc[ti][tj] = __builtin_amdgcn_mfma_f32_16x16x32_bf16(ah, bl[tj], acc[ti][tj], 0, 0, 0);
        acc[ti][tj] = __builtin_amdgcn_mfma_f32_16x16x32_bf16(al, bh[tj], acc[ti][tj], 0, 0, 0);
      }
    }
  }

  // Epilogue: 4 slices of 64 rows. Owning waves (wr == s>>1) deposit their
  // acc into LDS; all 512 threads then stream the slice out row-major.
  #pragma unroll
  for (int s = 0; s < 4; ++s) {
    if (wr == (s >> 1)) {
      int tbase = (s & 1) * 4;
      #pragma unroll
      for (int t = 0; t < 4; ++t)
        #pragma unroll
        for (int tj = 0; tj < 4; ++tj)
          #pragma unroll
          for (int q = 0; q < 4; ++q)
            sOut[t * 16 + kg * 4 + q][wc * 64 + tj * 16 + r16] = acc[tbase + t][tj][q];
    }
    __syncthreads();
    int srow0 = rowBlk + s * 64;
    #pragma unroll
    for (int p = 0; p < 8; ++p) {
      int idx = tid + p * 512;           // 4096 float4 per slice
      int row = idx >> 6, c4 = idx & 63; // one wave = one full 1KB row segment
      f32x4 v = *(const f32x4*)&sOut[row][c4 * 4];
      #pragma unroll
      for (int j = 0; j < 4; ++j) v[j] = 1.0f / (1.0f + __expf(-v[j]));
      int r = srow0 + row;
      int c = colBlk + c4 * 4;
      if (r < N) {
        if (c + 3 < N) {
          __builtin_nontemporal_store(v, (f32x4*)&out[(size_t)r * N + c]);
        } else {
          #pragma unroll
          for (int j = 0; j < 4; ++j)
            if (c + j < N) __builtin_nontemporal_store(v[j], &out[(size_t)r * N + c + j]);
        }
      }
    }
    __syncthreads();
  }
}

// ---------------------------------------------------------------------------
extern "C" void kernel_launch(void* const* d_in, const int* in_sizes, int n_in,
                              void* d_out, int out_size, void* d_ws, size_t ws_size,
                              hipStream_t stream) {
  const float* x = (const float*)d_in[0];
  const int* ei = (const int*)d_in[1];
  const float* W = (const float*)d_in[2];
  const float* att_s = (const float*)d_in[3];
  const float* att_d = (const float*)d_in[4];
  const float* bias = (const float*)d_in[5];

  const int N = in_sizes[0] / IN_DIM;   // 10000
  const int E = in_sizes[1] / 2;        // 320000
  const int NP2 = ((N + 255) / 256) * 256;   // 10240 (256-tile pad)

  float* out = (float*)d_out;
  float* embed_out = out + (size_t)N * N;

  // workspace layout (16B-aligned at ehi)
  float* h = (float*)d_ws;                      // N*128 f32
  float* a_src = h + (size_t)N * OUT_DIM;       // N
  float* a_dst = a_src + N;                     // N
  int* cnt = (int*)(a_dst + N);                 // N
  int* row_start = cnt + N;                     // N+4 (padded)
  int* cursor = row_start + (N + 4);            // N
  int* csr = cursor + N;                        // E
  uint16_t* ehi = (uint16_t*)(csr + E);         // NP2*128 bf16
  uint16_t* elo = ehi + (size_t)NP2 * OUT_DIM;  // NP2*128 bf16

  const int* e_src = ei;
  const int* e_dst = ei + E;

  k_h_gemm<<<dim3((N + 63) / 64), 256, 0, stream>>>(x, W, h, N);
  k_att<<<dim3((N * 64 + 255) / 256), 256, 0, stream>>>(h, att_s, att_d, a_src, a_dst, N);
  k_zero<<<dim3((N + 255) / 256), 256, 0, stream>>>(cnt, N);
  k_count<<<dim3((E + 255) / 256), 256, 0, stream>>>(e_dst, cnt, E);
  k_scan<<<dim3(1), 1024, 0, stream>>>(cnt, row_start, N);
  k_copy<<<dim3((N + 255) / 256), 256, 0, stream>>>(row_start, cursor, N);
  k_fill<<<dim3((E + 255) / 256), 256, 0, stream>>>(e_src, e_dst, cursor, csr, E);
  k_pad<<<dim3(8), 256, 0, stream>>>(ehi, elo, N, NP2);
  k_aggregate<<<dim3((N * 64 + 255) / 256), 256, 0, stream>>>(
      h, a_src, a_dst, row_start, csr, bias, embed_out, ehi, elo, N);
  const int nb = NP2 / 256;   // 40
  k_recon<<<dim3(nb * nb), 512, 0, stream>>>(ehi, elo, out, N, nb);
}